// Round 14
// baseline (446.557 us; speedup 1.0000x reference)
//
#include <hip/hip_runtime.h>
#include <hip/hip_fp16.h>
#include <math.h>

#define HDIM 768
#define NG   192        // HDIM/4 float4 groups
#define LMAX 512
#define RCAP 256        // max rows per half-region in compacted fp16 store

__device__ __forceinline__ float dot4(const float4 a, const float4 b) {
  return a.x * b.x + a.y * b.y + a.z * b.z + a.w * b.w;
}
__device__ __forceinline__ void fma4(float4& a, const float s, const float4 b) {
  a.x += s * b.x; a.y += s * b.y; a.z += s * b.z; a.w += s * b.w;
}
__device__ __forceinline__ void scale4(float4& a, const float s) {
  a.x *= s; a.y *= s; a.z *= s; a.w *= s;
}
__device__ __forceinline__ float4 h8_to_f4(uint2 v) {
  __half2 h0 = *reinterpret_cast<__half2*>(&v.x);
  __half2 h1 = *reinterpret_cast<__half2*>(&v.y);
  const float2 f0 = __half22float2(h0), f1 = __half22float2(h1);
  return make_float4(f0.x, f0.y, f1.x, f1.y);
}

// Wave64 sum via DPP (VALU pipe only).
__device__ __forceinline__ float wave_sum64(float x) {
  x += __int_as_float(__builtin_amdgcn_update_dpp(0, __float_as_int(x), 0xB1,  0xF, 0xF, true));
  x += __int_as_float(__builtin_amdgcn_update_dpp(0, __float_as_int(x), 0x4E,  0xF, 0xF, true));
  x += __int_as_float(__builtin_amdgcn_update_dpp(0, __float_as_int(x), 0x124, 0xF, 0xF, true));
  x += __int_as_float(__builtin_amdgcn_update_dpp(0, __float_as_int(x), 0x128, 0xF, 0xF, true));
  x += __int_as_float(__builtin_amdgcn_update_dpp(0, __float_as_int(x), 0x142, 0xF, 0xF, true));
  x += __int_as_float(__builtin_amdgcn_update_dpp(0, __float_as_int(x), 0x143, 0xF, 0xF, true));
  return __int_as_float(__builtin_amdgcn_readlane(__float_as_int(x), 63));
}

// ---------------- kernel 0: input-width detection ----------------
__global__ __launch_bounds__(256) void detect_slots(const unsigned* __restrict__ mask_w,
                                                    const unsigned* __restrict__ smap_w,
                                                    unsigned* __restrict__ slots,
                                                    int mask_words, int smap_words) {
  __shared__ unsigned red[2];
  const int b = blockIdx.x, tid = threadIdx.x;
  if (tid < 2) red[tid] = 0;
  __syncthreads();
  const int gtid = b * 256 + tid, gsz = gridDim.x * 256;
  unsigned acc = 0;
  for (int i = gtid; i < mask_words / 2; i += gsz) acc |= mask_w[2 * i + 1];
  unsigned acc2 = 0;
  for (int i = gtid; i < smap_words / 2; i += gsz) acc2 |= smap_w[2 * i + 1];
  if (acc)  atomicOr(&red[0], 1u);
  if (acc2) atomicOr(&red[1], 1u);
  __syncthreads();
  if (tid == 0) { slots[b] = red[0]; slots[64 + b] = red[1]; }
}

// ---------------- kernel 1: Wc = Wq^T * Wk, c0 = bq * Wk (proven) ----------------
__global__ __launch_bounds__(256) void prep_wc(const float* __restrict__ Wq,
                                               const float* __restrict__ Wk,
                                               const float* __restrict__ bq,
                                               float* __restrict__ Wc,
                                               float* __restrict__ c0, int H) {
  __shared__ float As[16][33];
  __shared__ float Bs[16][65];
  __shared__ float bqs[16];
  const int i0 = blockIdx.x * 32, j0 = blockIdx.y * 64;
  const int idx = threadIdx.x;
  const int li = idx & 31, lk = idx >> 5;
  const int lj = idx & 63, lk2 = idx >> 6;
  const int tc = idx & 15, tr = idx >> 4;
  float c[2][4] = {{0.f,0.f,0.f,0.f},{0.f,0.f,0.f,0.f}};
  float cb[4] = {0.f,0.f,0.f,0.f};
  const bool bias_lane = (blockIdx.x == 0) && (tr == 0);
  for (int o0 = 0; o0 < H; o0 += 16) {
    __syncthreads();
    As[lk][li]       = Wq[(size_t)(o0 + lk) * H + i0 + li];
    As[lk + 8][li]   = Wq[(size_t)(o0 + lk + 8) * H + i0 + li];
    Bs[lk2][lj]      = Wk[(size_t)(o0 + lk2) * H + j0 + lj];
    Bs[lk2 + 4][lj]  = Wk[(size_t)(o0 + lk2 + 4) * H + j0 + lj];
    Bs[lk2 + 8][lj]  = Wk[(size_t)(o0 + lk2 + 8) * H + j0 + lj];
    Bs[lk2 + 12][lj] = Wk[(size_t)(o0 + lk2 + 12) * H + j0 + lj];
    if (idx < 16) bqs[idx] = bq[o0 + idx];
    __syncthreads();
#pragma unroll
    for (int k = 0; k < 16; ++k) {
      const float a0 = As[k][tr * 2], a1 = As[k][tr * 2 + 1];
      const float b0 = Bs[k][tc * 4],     b1 = Bs[k][tc * 4 + 1];
      const float b2 = Bs[k][tc * 4 + 2], b3 = Bs[k][tc * 4 + 3];
      c[0][0] += a0 * b0; c[0][1] += a0 * b1; c[0][2] += a0 * b2; c[0][3] += a0 * b3;
      c[1][0] += a1 * b0; c[1][1] += a1 * b1; c[1][2] += a1 * b2; c[1][3] += a1 * b3;
      if (bias_lane) {
        const float bv = bqs[k];
        cb[0] += bv * b0; cb[1] += bv * b1; cb[2] += bv * b2; cb[3] += bv * b3;
      }
    }
  }
#pragma unroll
  for (int j = 0; j < 4; ++j) {
    Wc[(size_t)(i0 + tr * 2) * H + j0 + tc * 4 + j]     = c[0][j];
    Wc[(size_t)(i0 + tr * 2 + 1) * H + j0 + tc * 4 + j] = c[1][j];
  }
  if (bias_lane) {
#pragma unroll
    for (int j = 0; j < 4; ++j) c0[j0 + tc * 4 + j] = cb[j];
  }
}

// ---------------- kernel 2a: passA — half-sums + fp16 compacted store ----------------
// block (n, half), 384 thr. Streams all rows of the half (mean partial) and
// writes VALID rows fp16-compacted to hsc[bid]. Also writes nvalid[bid].
__global__ __launch_bounds__(384) void passA(const float* __restrict__ hs,
                                             const unsigned* __restrict__ mask_w,
                                             const unsigned* __restrict__ slots,
                                             float* __restrict__ part,
                                             int* __restrict__ nvalid,
                                             __half* __restrict__ hsc, int L) {
  __shared__ float4 red2[NG];
  __shared__ int cpos[RCAP];
  __shared__ int mrow[RCAP];
  __shared__ unsigned mfl;
  const int bid = blockIdx.x, n = bid >> 1, half = bid & 1;
  const int tid = threadIdx.x, lane = tid & 63;
  const int Lh = L / 2, r0 = half * Lh;

  if (tid == 0) mfl = 0u;
  __syncthreads();
  if (tid < 64 && slots[tid]) atomicOr(&mfl, 1u);
  __syncthreads();
  const int m32 = (mfl != 0);
  if (tid < Lh) {
    const size_t idx = (size_t)n * L + r0 + tid;
    mrow[tid] = (int)(m32 ? mask_w[idx] : mask_w[2 * idx]);
  }
  __syncthreads();

  // all-wave duplicated compaction -> cpos[l] (compact slot or -1), nv
  int nv = 0;
  for (int seg = 0; seg < Lh; seg += 64) {
    const int mv = mrow[seg + lane];
    const unsigned long long bal = __ballot(mv != 0);
    const int rank = __popcll(bal & ((1ull << lane) - 1ull));
    cpos[seg + lane] = (mv != 0) ? (nv + rank) : -1;
    nv += __popcll(bal);
  }

  const int sub = tid / NG, t = tid - sub * NG;
  const float4* hb = reinterpret_cast<const float4*>(hs) + ((size_t)n * L + r0) * NG;
  __half* reg = hsc + (size_t)bid * (RCAP * HDIM);
  float ax = 0.f, ay = 0.f, az = 0.f, aw = 0.f;

  auto st16 = [&](const float4 u, int cp) {
    __half2 h0 = __floats2half2_rn(u.x, u.y);
    __half2 h1 = __floats2half2_rn(u.z, u.w);
    uint2 pk;
    pk.x = *reinterpret_cast<unsigned*>(&h0);
    pk.y = *reinterpret_cast<unsigned*>(&h1);
    reinterpret_cast<uint2*>(reg + (size_t)cp * HDIM)[t] = pk;
  };

  int l = sub;
  for (; l + 16 <= Lh; l += 16) {
    float4 u[8];
#pragma unroll
    for (int i = 0; i < 8; ++i) u[i] = hb[(size_t)(l + 2 * i) * NG + t];
#pragma unroll
    for (int i = 0; i < 8; ++i) { ax += u[i].x; ay += u[i].y; az += u[i].z; aw += u[i].w; }
#pragma unroll
    for (int i = 0; i < 8; ++i) {
      const int cp = cpos[l + 2 * i];
      if (cp >= 0) st16(u[i], cp);
    }
  }
  for (; l < Lh; l += 2) {
    const float4 u = hb[(size_t)l * NG + t];
    ax += u.x; ay += u.y; az += u.z; aw += u.w;
    const int cp = cpos[l];
    if (cp >= 0) st16(u, cp);
  }

  if (sub == 1) { float4 o; o.x = ax; o.y = ay; o.z = az; o.w = aw; red2[t] = o; }
  __syncthreads();
  if (sub == 0) {
    const float4 r = red2[t];
    float4 o; o.x = ax + r.x; o.y = ay + r.y; o.z = az + r.z; o.w = aw + r.w;
    reinterpret_cast<float4*>(part + (size_t)bid * HDIM)[t] = o;
  }
  if (tid == 0) nvalid[bid] = nv;
}

// ---------------- kernel 3: V = (P0+P1)/L * Wc + c0 (proven r13) ----------------
__global__ __launch_bounds__(256) void gemmV(const float* __restrict__ P,
                                             const float* __restrict__ Wc,
                                             const float* __restrict__ c0,
                                             float* __restrict__ V,
                                             int M, int Nn, int K, float invL) {
  __shared__ float As[32][17];
  __shared__ float Bs[16][65];
  const int m0 = blockIdx.x * 32, n0 = blockIdx.y * 64;
  const int idx = threadIdx.x;
  const int lc = idx & 15, lr = idx >> 4;
  const int bc = idx & 63, br = idx >> 6;
  const int tc = idx & 15, tr = idx >> 4;
  float c[2][4] = {{0.f,0.f,0.f,0.f},{0.f,0.f,0.f,0.f}};
  for (int k0 = 0; k0 < K; k0 += 16) {
    __syncthreads();
    {
      const int m1 = m0 + lr, m2 = m0 + lr + 16;
      As[lr][lc]      = (P[(size_t)(2 * m1) * K + k0 + lc] + P[(size_t)(2 * m1 + 1) * K + k0 + lc]) * invL;
      As[lr + 16][lc] = (P[(size_t)(2 * m2) * K + k0 + lc] + P[(size_t)(2 * m2 + 1) * K + k0 + lc]) * invL;
    }
    Bs[br][bc]      = Wc[(size_t)(k0 + br) * Nn + n0 + bc];
    Bs[br + 4][bc]  = Wc[(size_t)(k0 + br + 4) * Nn + n0 + bc];
    Bs[br + 8][bc]  = Wc[(size_t)(k0 + br + 8) * Nn + n0 + bc];
    Bs[br + 12][bc] = Wc[(size_t)(k0 + br + 12) * Nn + n0 + bc];
    __syncthreads();
#pragma unroll
    for (int k = 0; k < 16; ++k) {
      const float a0 = As[tr * 2][k], a1 = As[tr * 2 + 1][k];
      const float b0 = Bs[k][tc * 4], b1 = Bs[k][tc * 4 + 1];
      const float b2 = Bs[k][tc * 4 + 2], b3 = Bs[k][tc * 4 + 3];
      c[0][0] += a0 * b0; c[0][1] += a0 * b1; c[0][2] += a0 * b2; c[0][3] += a0 * b3;
      c[1][0] += a1 * b0; c[1][1] += a1 * b1; c[1][2] += a1 * b2; c[1][3] += a1 * b3;
    }
  }
#pragma unroll
  for (int j = 0; j < 4; ++j) {
    const float bv = c0[n0 + tc * 4 + j];
    V[(size_t)(m0 + tr * 2) * Nn + n0 + tc * 4 + j]     = c[0][j] + bv;
    V[(size_t)(m0 + tr * 2 + 1) * Nn + n0 + tc * 4 + j] = c[1][j] + bv;
  }
}

// ---------------- kernel 4a: poolc — sequential fp16 compacted pool ----------------
// block (n, half), 256 thr, 4 waves. Reads rows 0..nv-1 of hsc[bid] (sequential).
// nv==0: exact fallback acc=part, (m,S)=(-1e9, Lh).
__global__ __launch_bounds__(256) void poolc(const __half* __restrict__ hsc,
                                             const int* __restrict__ nvalid,
                                             const float* __restrict__ part,
                                             const float* __restrict__ V,
                                             float* __restrict__ acc_out,
                                             float* __restrict__ ms_out, int L) {
  __shared__ float4 redv[4][NG];
  __shared__ float mw[4], sw[4];
  const int bid = blockIdx.x, n = bid >> 1;
  const int tid = threadIdx.x, w = tid >> 6, lane = tid & 63;
  const int Lh = L / 2;
  const int nv = nvalid[bid];

  if (nv == 0) {
#pragma unroll
    for (int p = 0; p < 3; ++p) {
      const int col = p * 256 + tid;
      acc_out[(size_t)bid * HDIM + col] = part[(size_t)bid * HDIM + col];
    }
    if (tid == 0) { ms_out[bid * 2] = -1e9f; ms_out[bid * 2 + 1] = (float)Lh; }
    return;
  }

  const float4* v4 = reinterpret_cast<const float4*>(V + (size_t)n * HDIM);
  const float4 vf0 = v4[lane], vf1 = v4[64 + lane], vf2 = v4[128 + lane];
  const uint2* rb = reinterpret_cast<const uint2*>(hsc + (size_t)bid * (RCAP * HDIM));
  const float scale = 1.0f / sqrtf((float)HDIM);

  const int cntw = (nv > w) ? ((nv - 1 - w) / 4 + 1) : 0;
  const int cmax = (nv + 3) / 4;
  const int jmax = (cmax + 3) & ~3;
  float m = -3.0e38f, ss = 0.f;
  float4 A0 = {0,0,0,0}, A1 = {0,0,0,0}, A2 = {0,0,0,0};
  uint2 xa[2][3], xb[2][3];

  auto ld = [&](uint2 (&X)[2][3], int j) {
#pragma unroll
    for (int u = 0; u < 2; ++u) {
      const int jj = j + u;
      const int rr = (jj < cntw) ? (4 * jj + w) : 0;
      const uint2* rp = rb + (size_t)rr * NG;
      X[u][0] = rp[lane]; X[u][1] = rp[64 + lane]; X[u][2] = rp[128 + lane];
    }
  };
  auto pr = [&](uint2 (&X)[2][3], int j) {
    float4 y[2][3];
    float s[2];
#pragma unroll
    for (int u = 0; u < 2; ++u) {
      y[u][0] = h8_to_f4(X[u][0]); y[u][1] = h8_to_f4(X[u][1]); y[u][2] = h8_to_f4(X[u][2]);
      const float p = wave_sum64(dot4(y[u][0], vf0) + dot4(y[u][1], vf1) + dot4(y[u][2], vf2));
      s[u] = (j + u < cntw) ? p * scale : -3.0e38f;
    }
    const float mc = fmaxf(s[0], s[1]);
    if (mc > m) {
      const float f = __expf(m - mc);
      ss *= f; scale4(A0, f); scale4(A1, f); scale4(A2, f);
      m = mc;
    }
#pragma unroll
    for (int u = 0; u < 2; ++u) {
      const float pq = (j + u < cntw) ? __expf(s[u] - m) : 0.f;
      ss += pq;
      fma4(A0, pq, y[u][0]); fma4(A1, pq, y[u][1]); fma4(A2, pq, y[u][2]);
    }
  };

  ld(xa, 0);
  for (int j = 0; j < jmax; j += 4) {
    ld(xb, j + 2);
    pr(xa, j);
    if (j + 4 < jmax) ld(xa, j + 4);
    pr(xb, j + 2);
  }

  if (lane == 0) { mw[w] = m; sw[w] = ss; }
  redv[w][lane]       = A0;
  redv[w][64 + lane]  = A1;
  redv[w][128 + lane] = A2;
  __syncthreads();
  const float M = fmaxf(fmaxf(mw[0], mw[1]), fmaxf(mw[2], mw[3]));
  const float f0 = __expf(mw[0] - M), f1 = __expf(mw[1] - M);
  const float f2 = __expf(mw[2] - M), f3 = __expf(mw[3] - M);
  const float S = sw[0] * f0 + sw[1] * f1 + sw[2] * f2 + sw[3] * f3;
  const float* redp = (const float*)redv;
#pragma unroll
  for (int p = 0; p < 3; ++p) {
    const int col = p * 256 + tid;
    acc_out[(size_t)bid * HDIM + col] =
        redp[col] * f0 + redp[HDIM + col] * f1 + redp[2 * HDIM + col] * f2 + redp[3 * HDIM + col] * f3;
  }
  if (tid == 0) { ms_out[bid * 2] = M; ms_out[bid * 2 + 1] = S; }
}

// ---------------- kernel 5: merge halves + segment mean (proven) ----------------
__global__ __launch_bounds__(256) void merge_segmean(const float* __restrict__ acc,
                                                     const float* __restrict__ ms,
                                                     const void* __restrict__ smap,
                                                     const unsigned* __restrict__ slots_s,
                                                     float* __restrict__ out, int N) {
  __shared__ unsigned fsh;
  const int t = blockIdx.x, tid = threadIdx.x;
  const int col = blockIdx.y * 256 + tid;
  if (tid == 0) {
    unsigned f = 0;
    for (int i = 0; i < 64; ++i) f |= slots_s[i];
    fsh = f;
  }
  __syncthreads();
  const int smap_is_i32 = (fsh != 0);
  float a = 0.f;
  int cnt = 0;
  for (int i = 0; i < N; ++i) {
    const int s = smap_is_i32 ? ((const int*)smap)[i]
                              : (int)((const long long*)smap)[i];
    if (s != t) continue;
    const float m0 = ms[(i * 2) * 2],     q0 = ms[(i * 2) * 2 + 1];
    const float m1 = ms[(i * 2 + 1) * 2], q1 = ms[(i * 2 + 1) * 2 + 1];
    const float M = fmaxf(m0, m1);
    const float f0 = __expf(m0 - M), f1 = __expf(m1 - M);
    const float S = q0 * f0 + q1 * f1;
    const float o = (acc[(size_t)(i * 2) * HDIM + col] * f0 +
                     acc[(size_t)(i * 2 + 1) * HDIM + col] * f1) / S;
    a += o; ++cnt;
  }
  out[(size_t)t * HDIM + col] = a / (float)(cnt > 0 ? cnt : 1);
}

// ================= fallback path: r11 champion fused kernel (verbatim) =================
__global__ __launch_bounds__(384) void fused(const float* __restrict__ hs,
                                             const unsigned* __restrict__ mask_w,
                                             const float* __restrict__ Wc,
                                             const float* __restrict__ c0,
                                             const unsigned* __restrict__ slots,
                                             float* __restrict__ pooled, int L) {
  __shared__ float4 red2[NG];
  __shared__ float4 meanv4[NG];
  __shared__ float4 vv4[NG];
  __shared__ float4 redv4[6][NG];
  __shared__ float mw[6], sw[6];
  __shared__ int   mrow[LMAX];
  __shared__ int   vidx[LMAX];
  __shared__ int   nv_sh;
  __shared__ unsigned mfl;
  const int n = blockIdx.x, tid = threadIdx.x;
  const int w = tid >> 6, lane = tid & 63;

  if (tid == 0) mfl = 0u;
  __syncthreads();
  if (tid < 64 && slots[tid]) atomicOr(&mfl, 1u);

  const int half = tid / NG, t = tid - half * NG;
  const float4* hb = reinterpret_cast<const float4*>(hs) + (size_t)n * L * NG;
  float ax = 0.f, ay = 0.f, az = 0.f, aw = 0.f;
  int l = half;
  for (; l + 16 <= L; l += 16) {
    float4 u[8];
#pragma unroll
    for (int i = 0; i < 8; ++i) u[i] = hb[(size_t)(l + 2 * i) * NG + t];
#pragma unroll
    for (int i = 0; i < 8; ++i) { ax += u[i].x; ay += u[i].y; az += u[i].z; aw += u[i].w; }
  }
  for (; l < L; l += 2) {
    float4 u = hb[(size_t)l * NG + t];
    ax += u.x; ay += u.y; az += u.z; aw += u.w;
  }
  if (half == 1) { float4 o; o.x = ax; o.y = ay; o.z = az; o.w = aw; red2[t] = o; }
  __syncthreads();

  if (half == 0) {
    const float inv = 1.0f / (float)L;
    const float4 r = red2[t];
    float4 o;
    o.x = (ax + r.x) * inv; o.y = (ay + r.y) * inv;
    o.z = (az + r.z) * inv; o.w = (aw + r.w) * inv;
    meanv4[t] = o;
  }
  const int mask_is_i32 = (mfl != 0);
  for (int tt = tid; tt < L; tt += 384) {
    const size_t idx = (size_t)n * L + tt;
    mrow[tt] = (int)(mask_is_i32 ? mask_w[idx] : mask_w[2 * idx]);
  }
  __syncthreads();

  if (w == 0) {
    int off = 0;
    for (int seg = 0; seg < L; seg += 64) {
      const int mv = mrow[seg + lane];
      const unsigned long long bal = __ballot(mv != 0);
      const int rank = __popcll(bal & ((1ull << lane) - 1ull));
      if (mv != 0) vidx[off + rank] = seg + lane;
      off += __popcll(bal);
    }
    if (lane == 0) nv_sh = off;
  }

  {
    const int c1 = tid, c2 = tid + 384;
    float acc1 = 0.f, acc2 = 0.f;
    const float* wp = Wc;
    for (int o = 0; o < HDIM; o += 4) {
      const float4 mv = meanv4[o >> 2];
      acc1 += mv.x * wp[c1] + mv.y * wp[HDIM + c1] + mv.z * wp[2 * HDIM + c1] + mv.w * wp[3 * HDIM + c1];
      acc2 += mv.x * wp[c2] + mv.y * wp[HDIM + c2] + mv.z * wp[2 * HDIM + c2] + mv.w * wp[3 * HDIM + c2];
      wp += 4 * HDIM;
    }
    ((float*)vv4)[c1] = acc1 + c0[c1];
    ((float*)vv4)[c2] = acc2 + c0[c2];
  }
  __syncthreads();

  const int nv = nv_sh;
  if (nv == 0) {
#pragma unroll
    for (int part = 0; part < 2; ++part) {
      const int col = part * 384 + tid;
      pooled[(size_t)n * HDIM + col] = ((const float*)meanv4)[col];
    }
    return;
  }

  const float4 vf0 = vv4[lane], vf1 = vv4[64 + lane], vf2 = vv4[128 + lane];
  const float scale = 1.0f / sqrtf((float)HDIM);
  const int cntw = (nv > w) ? ((nv - 1 - w) / 6 + 1) : 0;
  const int cmax = (nv + 5) / 6;
  const int jmax = (cmax + 3) & ~3;
  const int vidx0 = vidx[0];
  float m = -3.0e38f, ss = 0.f;
  float4 A0 = {0,0,0,0}, A1 = {0,0,0,0}, A2 = {0,0,0,0};
  float4 xa[2][3], xb[2][3];

  auto ld = [&](float4 (&X)[2][3], int j) {
#pragma unroll
    for (int u = 0; u < 2; ++u) {
      const int jj = j + u;
      const int rr = (jj < cntw) ? vidx[6 * jj + w] : vidx0;
      const float4* rp = hb + (size_t)rr * NG;
      X[u][0] = rp[lane]; X[u][1] = rp[64 + lane]; X[u][2] = rp[128 + lane];
    }
  };
  auto pr = [&](float4 (&X)[2][3], int j) {
    float s[2];
#pragma unroll
    for (int u = 0; u < 2; ++u) {
      const float p = wave_sum64(dot4(X[u][0], vf0) + dot4(X[u][1], vf1) + dot4(X[u][2], vf2));
      s[u] = (j + u < cntw) ? p * scale : -3.0e38f;
    }
    const float mc = fmaxf(s[0], s[1]);
    if (mc > m) {
      const float f = __expf(m - mc);
      ss *= f; scale4(A0, f); scale4(A1, f); scale4(A2, f);
      m = mc;
    }
#pragma unroll
    for (int u = 0; u < 2; ++u) {
      const float pq = (j + u < cntw) ? __expf(s[u] - m) : 0.f;
      ss += pq;
      fma4(A0, pq, X[u][0]); fma4(A1, pq, X[u][1]); fma4(A2, pq, X[u][2]);
    }
  };

  ld(xa, 0);
  for (int j = 0; j < jmax; j += 4) {
    ld(xb, j + 2);
    pr(xa, j);
    if (j + 4 < jmax) ld(xa, j + 4);
    pr(xb, j + 2);
  }

  if (lane == 0) { mw[w] = m; sw[w] = ss; }
  redv4[w][lane]       = A0;
  redv4[w][64 + lane]  = A1;
  redv4[w][128 + lane] = A2;
  __syncthreads();
  float M = mw[0];
#pragma unroll
  for (int j = 1; j < 6; ++j) M = fmaxf(M, mw[j]);
  float f[6], S = 0.f;
#pragma unroll
  for (int j = 0; j < 6; ++j) { f[j] = __expf(mw[j] - M); S += sw[j] * f[j]; }
  const float invS = 1.0f / S;
  const float* redp = (const float*)redv4;
#pragma unroll
  for (int part = 0; part < 2; ++part) {
    const int col = part * 384 + tid;
    float o = 0.f;
#pragma unroll
    for (int j = 0; j < 6; ++j) o += redp[j * HDIM + col] * f[j];
    pooled[(size_t)n * HDIM + col] = o * invS;
  }
}

__global__ __launch_bounds__(256) void segmean(const float* __restrict__ pooled,
                                               const void* __restrict__ smap,
                                               const unsigned* __restrict__ slots_s,
                                               float* __restrict__ out, int N) {
  __shared__ unsigned fsh;
  const int t = blockIdx.x, tid = threadIdx.x;
  const int col = blockIdx.y * 256 + tid;
  if (tid == 0) {
    unsigned f = 0;
    for (int i = 0; i < 64; ++i) f |= slots_s[i];
    fsh = f;
  }
  __syncthreads();
  const int smap_is_i32 = (fsh != 0);
  float a = 0.f;
  int cnt = 0;
  for (int i = 0; i < N; ++i) {
    const int s = smap_is_i32 ? ((const int*)smap)[i]
                              : (int)((const long long*)smap)[i];
    if (s == t) { a += pooled[(size_t)i * HDIM + col]; ++cnt; }
  }
  out[(size_t)t * HDIM + col] = a / (float)(cnt > 0 ? cnt : 1);
}

extern "C" void kernel_launch(void* const* d_in, const int* in_sizes, int n_in,
                              void* d_out, int out_size, void* d_ws, size_t ws_size,
                              hipStream_t stream) {
  const float*    hs     = (const float*)d_in[0];
  const unsigned* mask_w = (const unsigned*)d_in[1];
  const void*     smap   = d_in[2];
  const float*    Wq     = (const float*)d_in[3];
  const float*    bq     = (const float*)d_in[4];
  const float*    Wk     = (const float*)d_in[5];
  // d_in[6] = bk: dead (softmax-invariant)

  const int N = in_sizes[2];           // 512
  const int L = in_sizes[1] / N;       // 512
  const int H = in_sizes[4];           // 768
  const int T = out_size / H;          // 32
  const size_t NH = (size_t)N * H;
  (void)n_in;

  // ---- scratch budget for the fp16-compacted path ----
  const size_t f_words = (size_t)H * H + H + 2 * NH + NH + 2 * NH + 4 * N;  // Wc,c0,part,V,acc,ms
  const size_t i_bytes = (128 + 2 * (size_t)N) * 4;                         // slots, nvalid
  size_t hsc_off = (f_words * 4 + i_bytes + 255) & ~(size_t)255;
  const size_t hsc_bytes = (size_t)2 * N * RCAP * H * 2;                    // fp16
  const bool big = (ws_size >= hsc_off + hsc_bytes);

  if (big) {
    float* Wc   = (float*)d_ws;
    float* c0   = Wc + (size_t)H * H;
    float* part = c0 + H;
    float* V    = part + 2 * NH;
    float* acc  = V + NH;
    float* ms   = acc + 2 * NH;
    unsigned* slots = (unsigned*)(ms + 4 * N);
    int* nvalid = (int*)(slots + 128);
    __half* hsc = (__half*)((char*)d_ws + hsc_off);

    detect_slots<<<64, 256, 0, stream>>>(mask_w, (const unsigned*)smap, slots, N * L, N);
    prep_wc<<<dim3(H / 32, H / 64), 256, 0, stream>>>(Wq, Wk, bq, Wc, c0, H);
    passA<<<2 * N, 384, 0, stream>>>(hs, mask_w, slots, part, nvalid, hsc, L);
    gemmV<<<dim3(N / 32, H / 64), 256, 0, stream>>>(part, Wc, c0, V, N, H, H, 1.0f / (float)L);
    poolc<<<2 * N, 256, 0, stream>>>(hsc, nvalid, part, V, acc, ms, L);
    merge_segmean<<<dim3(T, 3), 256, 0, stream>>>(acc, ms, smap, slots + 64, (float*)d_out, N);
  } else {
    // r11 champion path
    float* Wc     = (float*)d_ws;
    float* c0     = Wc + (size_t)H * H;
    float* pooled = c0 + H;
    unsigned* slots = (unsigned*)(pooled + NH);

    detect_slots<<<64, 256, 0, stream>>>(mask_w, (const unsigned*)smap, slots, N * L, N);
    prep_wc<<<dim3(H / 32, H / 64), 256, 0, stream>>>(Wq, Wk, bq, Wc, c0, H);
    fused<<<N, 384, 0, stream>>>(hs, mask_w, Wc, c0, slots, pooled, L);
    segmean<<<dim3(T, 3), 256, 0, stream>>>(pooled, smap, slots + 64, (float*)d_out, N);
  }
}

// Round 15
// 364.143 us; speedup vs baseline: 1.2263x; 1.2263x over previous
//
#include <hip/hip_runtime.h>
#include <math.h>

#define HDIM 768
#define NG   192        // HDIM/4 float4 groups
#define LMAX 512

__device__ __forceinline__ float dot4(const float4 a, const float4 b) {
  return a.x * b.x + a.y * b.y + a.z * b.z + a.w * b.w;
}
__device__ __forceinline__ void fma4(float4& a, const float s, const float4 b) {
  a.x += s * b.x; a.y += s * b.y; a.z += s * b.z; a.w += s * b.w;
}
__device__ __forceinline__ void scale4(float4& a, const float s) {
  a.x *= s; a.y *= s; a.z *= s; a.w *= s;
}

// Wave64 sum via DPP (VALU pipe only).
__device__ __forceinline__ float wave_sum64(float x) {
  x += __int_as_float(__builtin_amdgcn_update_dpp(0, __float_as_int(x), 0xB1,  0xF, 0xF, true));
  x += __int_as_float(__builtin_amdgcn_update_dpp(0, __float_as_int(x), 0x4E,  0xF, 0xF, true));
  x += __int_as_float(__builtin_amdgcn_update_dpp(0, __float_as_int(x), 0x124, 0xF, 0xF, true));
  x += __int_as_float(__builtin_amdgcn_update_dpp(0, __float_as_int(x), 0x128, 0xF, 0xF, true));
  x += __int_as_float(__builtin_amdgcn_update_dpp(0, __float_as_int(x), 0x142, 0xF, 0xF, true));
  x += __int_as_float(__builtin_amdgcn_update_dpp(0, __float_as_int(x), 0x143, 0xF, 0xF, true));
  return __int_as_float(__builtin_amdgcn_readlane(__float_as_int(x), 63));
}

// ---------------- kernel 0: input-width detection (slot writes) ----------------
__global__ __launch_bounds__(256) void detect_slots(const unsigned* __restrict__ mask_w,
                                                    const unsigned* __restrict__ smap_w,
                                                    unsigned* __restrict__ slots,
                                                    int mask_words, int smap_words) {
  __shared__ unsigned red[2];
  const int b = blockIdx.x, tid = threadIdx.x;
  if (tid < 2) red[tid] = 0;
  __syncthreads();
  const int gtid = b * 256 + tid, gsz = gridDim.x * 256;
  unsigned acc = 0;
  for (int i = gtid; i < mask_words / 2; i += gsz) acc |= mask_w[2 * i + 1];
  unsigned acc2 = 0;
  for (int i = gtid; i < smap_words / 2; i += gsz) acc2 |= smap_w[2 * i + 1];
  if (acc)  atomicOr(&red[0], 1u);
  if (acc2) atomicOr(&red[1], 1u);
  __syncthreads();
  if (tid == 0) { slots[b] = red[0]; slots[64 + b] = red[1]; }
}

// ---------------- kernel 1: Wc = Wq^T * Wk, c0 = bq * Wk ----------------
__global__ __launch_bounds__(256) void prep_wc(const float* __restrict__ Wq,
                                               const float* __restrict__ Wk,
                                               const float* __restrict__ bq,
                                               float* __restrict__ Wc,
                                               float* __restrict__ c0, int H) {
  __shared__ float As[16][33];
  __shared__ float Bs[16][65];
  __shared__ float bqs[16];
  const int i0 = blockIdx.x * 32, j0 = blockIdx.y * 64;
  const int idx = threadIdx.x;
  const int li = idx & 31, lk = idx >> 5;
  const int lj = idx & 63, lk2 = idx >> 6;
  const int tc = idx & 15, tr = idx >> 4;
  float c[2][4] = {{0.f,0.f,0.f,0.f},{0.f,0.f,0.f,0.f}};
  float cb[4] = {0.f,0.f,0.f,0.f};
  const bool bias_lane = (blockIdx.x == 0) && (tr == 0);
  for (int o0 = 0; o0 < H; o0 += 16) {
    __syncthreads();
    As[lk][li]       = Wq[(size_t)(o0 + lk) * H + i0 + li];
    As[lk + 8][li]   = Wq[(size_t)(o0 + lk + 8) * H + i0 + li];
    Bs[lk2][lj]      = Wk[(size_t)(o0 + lk2) * H + j0 + lj];
    Bs[lk2 + 4][lj]  = Wk[(size_t)(o0 + lk2 + 4) * H + j0 + lj];
    Bs[lk2 + 8][lj]  = Wk[(size_t)(o0 + lk2 + 8) * H + j0 + lj];
    Bs[lk2 + 12][lj] = Wk[(size_t)(o0 + lk2 + 12) * H + j0 + lj];
    if (idx < 16) bqs[idx] = bq[o0 + idx];
    __syncthreads();
#pragma unroll
    for (int k = 0; k < 16; ++k) {
      const float a0 = As[k][tr * 2], a1 = As[k][tr * 2 + 1];
      const float b0 = Bs[k][tc * 4],     b1 = Bs[k][tc * 4 + 1];
      const float b2 = Bs[k][tc * 4 + 2], b3 = Bs[k][tc * 4 + 3];
      c[0][0] += a0 * b0; c[0][1] += a0 * b1; c[0][2] += a0 * b2; c[0][3] += a0 * b3;
      c[1][0] += a1 * b0; c[1][1] += a1 * b1; c[1][2] += a1 * b2; c[1][3] += a1 * b3;
      if (bias_lane) {
        const float bv = bqs[k];
        cb[0] += bv * b0; cb[1] += bv * b1; cb[2] += bv * b2; cb[3] += bv * b3;
      }
    }
  }
#pragma unroll
  for (int j = 0; j < 4; ++j) {
    Wc[(size_t)(i0 + tr * 2) * H + j0 + tc * 4 + j]     = c[0][j];
    Wc[(size_t)(i0 + tr * 2 + 1) * H + j0 + tc * 4 + j] = c[1][j];
  }
  if (bias_lane) {
#pragma unroll
    for (int j = 0; j < 4; ++j) c0[j0 + tc * 4 + j] = cb[j];
  }
}

// ---------------- kernel 2: fused mean -> GEMV -> scores/softmax/pool ----------------
// r11 structure; ONLY change: pass-2 wave ownership is a CONTIGUOUS strip of the
// compacted valid-row list (per-wave sequential streams, drift-immune) instead
// of 6-way interleave.
__global__ __launch_bounds__(384) void fused(const float* __restrict__ hs,
                                             const unsigned* __restrict__ mask_w,
                                             const float* __restrict__ Wc,
                                             const float* __restrict__ c0,
                                             const unsigned* __restrict__ slots,
                                             float* __restrict__ pooled, int L) {
  __shared__ float4 red2[NG];
  __shared__ float4 meanv4[NG];
  __shared__ float4 vv4[NG];
  __shared__ float4 redv4[6][NG];
  __shared__ float mw[6], sw[6];
  __shared__ int   mrow[LMAX];
  __shared__ int   vidx[LMAX];
  __shared__ int   nv_sh;
  __shared__ unsigned mfl;
  const int n = blockIdx.x, tid = threadIdx.x;
  const int w = tid >> 6, lane = tid & 63;

  if (tid == 0) mfl = 0u;
  __syncthreads();
  if (tid < 64 && slots[tid]) atomicOr(&mfl, 1u);

  // ---- pass 1: mean over L (forward stream) ----
  const int half = tid / NG, t = tid - half * NG;
  const float4* hb = reinterpret_cast<const float4*>(hs) + (size_t)n * L * NG;
  float ax = 0.f, ay = 0.f, az = 0.f, aw = 0.f;
  int l = half;
  for (; l + 16 <= L; l += 16) {
    float4 u[8];
#pragma unroll
    for (int i = 0; i < 8; ++i) u[i] = hb[(size_t)(l + 2 * i) * NG + t];
#pragma unroll
    for (int i = 0; i < 8; ++i) { ax += u[i].x; ay += u[i].y; az += u[i].z; aw += u[i].w; }
  }
  for (; l < L; l += 2) {
    float4 u = hb[(size_t)l * NG + t];
    ax += u.x; ay += u.y; az += u.z; aw += u.w;
  }
  if (half == 1) { float4 o; o.x = ax; o.y = ay; o.z = az; o.w = aw; red2[t] = o; }
  __syncthreads();

  if (half == 0) {
    const float inv = 1.0f / (float)L;
    const float4 r = red2[t];
    float4 o;
    o.x = (ax + r.x) * inv; o.y = (ay + r.y) * inv;
    o.z = (az + r.z) * inv; o.w = (aw + r.w) * inv;
    meanv4[t] = o;
  }
  const int mask_is_i32 = (mfl != 0);
  for (int tt = tid; tt < L; tt += 384) {
    const size_t idx = (size_t)n * L + tt;
    mrow[tt] = (int)(mask_is_i32 ? mask_w[idx] : mask_w[2 * idx]);
  }
  __syncthreads();

  // ---- wave 0: deterministic compaction of valid rows (ballot scan) ----
  if (w == 0) {
    int off = 0;
    for (int seg = 0; seg < L; seg += 64) {
      const int mv = mrow[seg + lane];
      const unsigned long long bal = __ballot(mv != 0);
      const int rank = __popcll(bal & ((1ull << lane) - 1ull));
      if (mv != 0) vidx[off + rank] = seg + lane;
      off += __popcll(bal);
    }
    if (lane == 0) nv_sh = off;
  }

  // ---- GEMV: v = mean * Wc + c0 ----
  {
    const int c1 = tid, c2 = tid + 384;
    float acc1 = 0.f, acc2 = 0.f;
    const float* wp = Wc;
    for (int o = 0; o < HDIM; o += 4) {
      const float4 mv = meanv4[o >> 2];
      acc1 += mv.x * wp[c1] + mv.y * wp[HDIM + c1] + mv.z * wp[2 * HDIM + c1] + mv.w * wp[3 * HDIM + c1];
      acc2 += mv.x * wp[c2] + mv.y * wp[HDIM + c2] + mv.z * wp[2 * HDIM + c2] + mv.w * wp[3 * HDIM + c2];
      wp += 4 * HDIM;
    }
    ((float*)vv4)[c1] = acc1 + c0[c1];
    ((float*)vv4)[c2] = acc2 + c0[c2];
  }
  __syncthreads();   // vv4, vidx, nv ready

  const int nv = nv_sh;
  if (nv == 0) {
    // all rows masked: reference softmax is uniform -> pooled = mean
#pragma unroll
    for (int part = 0; part < 2; ++part) {
      const int col = part * 384 + tid;
      pooled[(size_t)n * HDIM + col] = ((const float*)meanv4)[col];
    }
    return;
  }

  // ---- pass 2: contiguous strip per wave over the compact list ----
  const float4 vf0 = vv4[lane], vf1 = vv4[64 + lane], vf2 = vv4[128 + lane];
  const float scale = 1.0f / sqrtf((float)HDIM);
  const int q = nv / 6, r6_ = nv % 6;
  const int s0w  = w * q + (w < r6_ ? w : r6_);   // strip start for this wave
  const int cntw = q + (w < r6_ ? 1 : 0);         // strip length
  const int jmaxw = (cntw + 3) & ~3;              // per-wave loop bound (wave-uniform)
  float m = -3.0e38f, ss = 0.f;
  float4 A0 = {0,0,0,0}, A1 = {0,0,0,0}, A2 = {0,0,0,0};
  float4 xa[2][3], xb[2][3];

  auto ld = [&](float4 (&X)[2][3], int j) {
#pragma unroll
    for (int u = 0; u < 2; ++u) {
      const int jj = j + u;
      const int rr = (jj < cntw) ? vidx[s0w + jj] : vidx[0];
      const float4* rp = hb + (size_t)rr * NG;
      X[u][0] = rp[lane]; X[u][1] = rp[64 + lane]; X[u][2] = rp[128 + lane];
    }
  };
  auto pr = [&](float4 (&X)[2][3], int j) {
    float s[2];
#pragma unroll
    for (int u = 0; u < 2; ++u) {
      const float p = wave_sum64(dot4(X[u][0], vf0) + dot4(X[u][1], vf1) + dot4(X[u][2], vf2));
      s[u] = (j + u < cntw) ? p * scale : -3.0e38f;
    }
    const float mc = fmaxf(s[0], s[1]);
    if (mc > m) {   // defer-rescale (wave-uniform)
      const float f = __expf(m - mc);
      ss *= f; scale4(A0, f); scale4(A1, f); scale4(A2, f);
      m = mc;
    }
#pragma unroll
    for (int u = 0; u < 2; ++u) {
      const float pq = (j + u < cntw) ? __expf(s[u] - m) : 0.f;
      ss += pq;
      fma4(A0, pq, X[u][0]); fma4(A1, pq, X[u][1]); fma4(A2, pq, X[u][2]);
    }
  };

  if (jmaxw > 0) {
    ld(xa, 0);
    for (int j = 0; j < jmaxw; j += 4) {
      ld(xb, j + 2);
      pr(xa, j);
      if (j + 4 < jmaxw) ld(xa, j + 4);
      pr(xb, j + 2);
    }
  }

  // ---- 6-way split-softmax merge ----
  if (lane == 0) { mw[w] = m; sw[w] = ss; }
  redv4[w][lane]       = A0;
  redv4[w][64 + lane]  = A1;
  redv4[w][128 + lane] = A2;
  __syncthreads();
  float M = mw[0];
#pragma unroll
  for (int j = 1; j < 6; ++j) M = fmaxf(M, mw[j]);
  float f[6], S = 0.f;
#pragma unroll
  for (int j = 0; j < 6; ++j) { f[j] = __expf(mw[j] - M); S += sw[j] * f[j]; }
  const float invS = 1.0f / S;
  const float* redp = (const float*)redv4;
#pragma unroll
  for (int part = 0; part < 2; ++part) {
    const int col = part * 384 + tid;
    float o = 0.f;
#pragma unroll
    for (int j = 0; j < 6; ++j) o += redp[j * HDIM + col] * f[j];
    pooled[(size_t)n * HDIM + col] = o * invS;
  }
}

// ---------------- kernel 3: segment mean ----------------
__global__ __launch_bounds__(256) void segmean(const float* __restrict__ pooled,
                                               const void* __restrict__ smap,
                                               const unsigned* __restrict__ slots_s,
                                               float* __restrict__ out, int N) {
  __shared__ unsigned fsh;
  const int t = blockIdx.x, tid = threadIdx.x;
  const int col = blockIdx.y * 256 + tid;
  if (tid == 0) {
    unsigned f = 0;
    for (int i = 0; i < 64; ++i) f |= slots_s[i];
    fsh = f;
  }
  __syncthreads();
  const int smap_is_i32 = (fsh != 0);
  float a = 0.f;
  int cnt = 0;
  for (int i = 0; i < N; ++i) {
    const int s = smap_is_i32 ? ((const int*)smap)[i]
                              : (int)((const long long*)smap)[i];
    if (s == t) { a += pooled[(size_t)i * HDIM + col]; ++cnt; }
  }
  out[(size_t)t * HDIM + col] = a / (float)(cnt > 0 ? cnt : 1);
}

extern "C" void kernel_launch(void* const* d_in, const int* in_sizes, int n_in,
                              void* d_out, int out_size, void* d_ws, size_t ws_size,
                              hipStream_t stream) {
  const float*    hs     = (const float*)d_in[0];
  const unsigned* mask_w = (const unsigned*)d_in[1];
  const void*     smap   = d_in[2];
  const float*    Wq     = (const float*)d_in[3];
  const float*    bq     = (const float*)d_in[4];
  const float*    Wk     = (const float*)d_in[5];
  // d_in[6] = bk: dead (adds per-row constant to scores -> softmax-invariant)

  const int N = in_sizes[2];           // 512
  const int L = in_sizes[1] / N;       // 512
  const int H = in_sizes[4];           // 768 (== HDIM)
  const int T = out_size / H;          // 32

  float* Wc     = (float*)d_ws;                    // [H,H]
  float* c0     = Wc + (size_t)H * H;              // [H]
  float* pooled = c0 + H;                          // [N,H]
  unsigned* slots = (unsigned*)(pooled + (size_t)N * H);  // [128]
  (void)ws_size; (void)n_in;

  detect_slots<<<64, 256, 0, stream>>>(mask_w, (const unsigned*)smap, slots, N * L, N);
  prep_wc<<<dim3(H / 32, H / 64), 256, 0, stream>>>(Wq, Wk, bq, Wc, c0, H);
  fused<<<N, 384, 0, stream>>>(hs, mask_w, Wc, c0, slots, pooled, L);
  segmean<<<dim3(T, 3), 256, 0, stream>>>(pooled, smap, slots + 64, (float*)d_out, N);
}

// Round 16
// 362.363 us; speedup vs baseline: 1.2323x; 1.0049x over previous
//
#include <hip/hip_runtime.h>
#include <math.h>

#define HDIM 768
#define NG   192        // HDIM/4 float4 groups
#define LMAX 512

__device__ __forceinline__ float dot4(const float4 a, const float4 b) {
  return a.x * b.x + a.y * b.y + a.z * b.z + a.w * b.w;
}
__device__ __forceinline__ void fma4(float4& a, const float s, const float4 b) {
  a.x += s * b.x; a.y += s * b.y; a.z += s * b.z; a.w += s * b.w;
}
__device__ __forceinline__ void scale4(float4& a, const float s) {
  a.x *= s; a.y *= s; a.z *= s; a.w *= s;
}

// Wave64 sum via DPP (VALU pipe only).
__device__ __forceinline__ float wave_sum64(float x) {
  x += __int_as_float(__builtin_amdgcn_update_dpp(0, __float_as_int(x), 0xB1,  0xF, 0xF, true));
  x += __int_as_float(__builtin_amdgcn_update_dpp(0, __float_as_int(x), 0x4E,  0xF, 0xF, true));
  x += __int_as_float(__builtin_amdgcn_update_dpp(0, __float_as_int(x), 0x124, 0xF, 0xF, true));
  x += __int_as_float(__builtin_amdgcn_update_dpp(0, __float_as_int(x), 0x128, 0xF, 0xF, true));
  x += __int_as_float(__builtin_amdgcn_update_dpp(0, __float_as_int(x), 0x142, 0xF, 0xF, true));
  x += __int_as_float(__builtin_amdgcn_update_dpp(0, __float_as_int(x), 0x143, 0xF, 0xF, true));
  return __int_as_float(__builtin_amdgcn_readlane(__float_as_int(x), 63));
}

// ---------------- kernel 0: input-width detection (slot writes) ----------------
__global__ __launch_bounds__(256) void detect_slots(const unsigned* __restrict__ mask_w,
                                                    const unsigned* __restrict__ smap_w,
                                                    unsigned* __restrict__ slots,
                                                    int mask_words, int smap_words) {
  __shared__ unsigned red[2];
  const int b = blockIdx.x, tid = threadIdx.x;
  if (tid < 2) red[tid] = 0;
  __syncthreads();
  const int gtid = b * 256 + tid, gsz = gridDim.x * 256;
  unsigned acc = 0;
  for (int i = gtid; i < mask_words / 2; i += gsz) acc |= mask_w[2 * i + 1];
  unsigned acc2 = 0;
  for (int i = gtid; i < smap_words / 2; i += gsz) acc2 |= smap_w[2 * i + 1];
  if (acc)  atomicOr(&red[0], 1u);
  if (acc2) atomicOr(&red[1], 1u);
  __syncthreads();
  if (tid == 0) { slots[b] = red[0]; slots[64 + b] = red[1]; }
}

// ---------------- kernel 1: Wc = Wq^T * Wk, c0 = bq * Wk ----------------
__global__ __launch_bounds__(256) void prep_wc(const float* __restrict__ Wq,
                                               const float* __restrict__ Wk,
                                               const float* __restrict__ bq,
                                               float* __restrict__ Wc,
                                               float* __restrict__ c0, int H) {
  __shared__ float As[16][33];
  __shared__ float Bs[16][65];
  __shared__ float bqs[16];
  const int i0 = blockIdx.x * 32, j0 = blockIdx.y * 64;
  const int idx = threadIdx.x;
  const int li = idx & 31, lk = idx >> 5;
  const int lj = idx & 63, lk2 = idx >> 6;
  const int tc = idx & 15, tr = idx >> 4;
  float c[2][4] = {{0.f,0.f,0.f,0.f},{0.f,0.f,0.f,0.f}};
  float cb[4] = {0.f,0.f,0.f,0.f};
  const bool bias_lane = (blockIdx.x == 0) && (tr == 0);
  for (int o0 = 0; o0 < H; o0 += 16) {
    __syncthreads();
    As[lk][li]       = Wq[(size_t)(o0 + lk) * H + i0 + li];
    As[lk + 8][li]   = Wq[(size_t)(o0 + lk + 8) * H + i0 + li];
    Bs[lk2][lj]      = Wk[(size_t)(o0 + lk2) * H + j0 + lj];
    Bs[lk2 + 4][lj]  = Wk[(size_t)(o0 + lk2 + 4) * H + j0 + lj];
    Bs[lk2 + 8][lj]  = Wk[(size_t)(o0 + lk2 + 8) * H + j0 + lj];
    Bs[lk2 + 12][lj] = Wk[(size_t)(o0 + lk2 + 12) * H + j0 + lj];
    if (idx < 16) bqs[idx] = bq[o0 + idx];
    __syncthreads();
#pragma unroll
    for (int k = 0; k < 16; ++k) {
      const float a0 = As[k][tr * 2], a1 = As[k][tr * 2 + 1];
      const float b0 = Bs[k][tc * 4],     b1 = Bs[k][tc * 4 + 1];
      const float b2 = Bs[k][tc * 4 + 2], b3 = Bs[k][tc * 4 + 3];
      c[0][0] += a0 * b0; c[0][1] += a0 * b1; c[0][2] += a0 * b2; c[0][3] += a0 * b3;
      c[1][0] += a1 * b0; c[1][1] += a1 * b1; c[1][2] += a1 * b2; c[1][3] += a1 * b3;
      if (bias_lane) {
        const float bv = bqs[k];
        cb[0] += bv * b0; cb[1] += bv * b1; cb[2] += bv * b2; cb[3] += bv * b3;
      }
    }
  }
#pragma unroll
  for (int j = 0; j < 4; ++j) {
    Wc[(size_t)(i0 + tr * 2) * H + j0 + tc * 4 + j]     = c[0][j];
    Wc[(size_t)(i0 + tr * 2 + 1) * H + j0 + tc * 4 + j] = c[1][j];
  }
  if (bias_lane) {
#pragma unroll
    for (int j = 0; j < 4; ++j) c0[j0 + tc * 4 + j] = cb[j];
  }
}

// ---------------- kernel 2: fused mean -> GEMV -> scores/softmax/pool ----------------
// r15 structure; ONLY change: pass-2 uses FOUR single-row buffers, modulo-
// scheduled (statically unrolled x4) so ~3 rows (~9 KB/wave) are in flight
// at all times instead of ~1 batch.
__global__ __launch_bounds__(384) void fused(const float* __restrict__ hs,
                                             const unsigned* __restrict__ mask_w,
                                             const float* __restrict__ Wc,
                                             const float* __restrict__ c0,
                                             const unsigned* __restrict__ slots,
                                             float* __restrict__ pooled, int L) {
  __shared__ float4 red2[NG];
  __shared__ float4 meanv4[NG];
  __shared__ float4 vv4[NG];
  __shared__ float4 redv4[6][NG];
  __shared__ float mw[6], sw[6];
  __shared__ int   mrow[LMAX];
  __shared__ int   vidx[LMAX];
  __shared__ int   nv_sh;
  __shared__ unsigned mfl;
  const int n = blockIdx.x, tid = threadIdx.x;
  const int w = tid >> 6, lane = tid & 63;

  if (tid == 0) mfl = 0u;
  __syncthreads();
  if (tid < 64 && slots[tid]) atomicOr(&mfl, 1u);

  // ---- pass 1: mean over L (forward stream) ----
  const int half = tid / NG, t = tid - half * NG;
  const float4* hb = reinterpret_cast<const float4*>(hs) + (size_t)n * L * NG;
  float ax = 0.f, ay = 0.f, az = 0.f, aw = 0.f;
  int l = half;
  for (; l + 16 <= L; l += 16) {
    float4 u[8];
#pragma unroll
    for (int i = 0; i < 8; ++i) u[i] = hb[(size_t)(l + 2 * i) * NG + t];
#pragma unroll
    for (int i = 0; i < 8; ++i) { ax += u[i].x; ay += u[i].y; az += u[i].z; aw += u[i].w; }
  }
  for (; l < L; l += 2) {
    float4 u = hb[(size_t)l * NG + t];
    ax += u.x; ay += u.y; az += u.z; aw += u.w;
  }
  if (half == 1) { float4 o; o.x = ax; o.y = ay; o.z = az; o.w = aw; red2[t] = o; }
  __syncthreads();

  if (half == 0) {
    const float inv = 1.0f / (float)L;
    const float4 r = red2[t];
    float4 o;
    o.x = (ax + r.x) * inv; o.y = (ay + r.y) * inv;
    o.z = (az + r.z) * inv; o.w = (aw + r.w) * inv;
    meanv4[t] = o;
  }
  const int mask_is_i32 = (mfl != 0);
  for (int tt = tid; tt < L; tt += 384) {
    const size_t idx = (size_t)n * L + tt;
    mrow[tt] = (int)(mask_is_i32 ? mask_w[idx] : mask_w[2 * idx]);
  }
  __syncthreads();

  // ---- wave 0: deterministic compaction of valid rows (ballot scan) ----
  if (w == 0) {
    int off = 0;
    for (int seg = 0; seg < L; seg += 64) {
      const int mv = mrow[seg + lane];
      const unsigned long long bal = __ballot(mv != 0);
      const int rank = __popcll(bal & ((1ull << lane) - 1ull));
      if (mv != 0) vidx[off + rank] = seg + lane;
      off += __popcll(bal);
    }
    if (lane == 0) nv_sh = off;
  }

  // ---- GEMV: v = mean * Wc + c0 ----
  {
    const int c1 = tid, c2 = tid + 384;
    float acc1 = 0.f, acc2 = 0.f;
    const float* wp = Wc;
    for (int o = 0; o < HDIM; o += 4) {
      const float4 mv = meanv4[o >> 2];
      acc1 += mv.x * wp[c1] + mv.y * wp[HDIM + c1] + mv.z * wp[2 * HDIM + c1] + mv.w * wp[3 * HDIM + c1];
      acc2 += mv.x * wp[c2] + mv.y * wp[HDIM + c2] + mv.z * wp[2 * HDIM + c2] + mv.w * wp[3 * HDIM + c2];
      wp += 4 * HDIM;
    }
    ((float*)vv4)[c1] = acc1 + c0[c1];
    ((float*)vv4)[c2] = acc2 + c0[c2];
  }
  __syncthreads();   // vv4, vidx, nv ready

  const int nv = nv_sh;
  if (nv == 0) {
    // all rows masked: reference softmax is uniform -> pooled = mean
#pragma unroll
    for (int part = 0; part < 2; ++part) {
      const int col = part * 384 + tid;
      pooled[(size_t)n * HDIM + col] = ((const float*)meanv4)[col];
    }
    return;
  }

  // ---- pass 2: contiguous strip per wave; 4 x 1-row modulo-scheduled pipeline ----
  const float4 vf0 = vv4[lane], vf1 = vv4[64 + lane], vf2 = vv4[128 + lane];
  const float scale = 1.0f / sqrtf((float)HDIM);
  const int q = nv / 6, r6_ = nv % 6;
  const int s0w  = w * q + (w < r6_ ? w : r6_);   // strip start for this wave
  const int cntw = q + (w < r6_ ? 1 : 0);         // strip length
  const int jmaxw = (cntw + 3) & ~3;              // multiple of 4 (wave-uniform)
  float m = -3.0e38f, ss = 0.f;
  float4 A0 = {0,0,0,0}, A1 = {0,0,0,0}, A2 = {0,0,0,0};
  float4 x0[3], x1[3], x2[3], x3[3];              // 4 single-row buffers (static idx)

  auto ld = [&](float4 (&X)[3], int j) {
    const int rr = (j < cntw) ? vidx[s0w + j] : vidx[0];
    const float4* rp = hb + (size_t)rr * NG;
    X[0] = rp[lane]; X[1] = rp[64 + lane]; X[2] = rp[128 + lane];
  };
  auto pr = [&](float4 (&X)[3], int j) {
    const float p = wave_sum64(dot4(X[0], vf0) + dot4(X[1], vf1) + dot4(X[2], vf2));
    const float s = (j < cntw) ? p * scale : -3.0e38f;
    if (s > m) {   // defer-rescale (wave-uniform)
      const float f = __expf(m - s);
      ss *= f; scale4(A0, f); scale4(A1, f); scale4(A2, f);
      m = s;
    }
    const float pq = (j < cntw) ? __expf(s - m) : 0.f;
    ss += pq;
    fma4(A0, pq, X[0]); fma4(A1, pq, X[1]); fma4(A2, pq, X[2]);
  };

  ld(x0, 0); ld(x1, 1); ld(x2, 2);                // 3 rows in flight
  for (int j = 0; j < jmaxw; j += 4) {
    ld(x3, j + 3); pr(x0, j);
    ld(x0, j + 4); pr(x1, j + 1);
    ld(x1, j + 5); pr(x2, j + 2);
    ld(x2, j + 6); pr(x3, j + 3);
  }

  // ---- 6-way split-softmax merge ----
  if (lane == 0) { mw[w] = m; sw[w] = ss; }
  redv4[w][lane]       = A0;
  redv4[w][64 + lane]  = A1;
  redv4[w][128 + lane] = A2;
  __syncthreads();
  float M = mw[0];
#pragma unroll
  for (int j = 1; j < 6; ++j) M = fmaxf(M, mw[j]);
  float f[6], S = 0.f;
#pragma unroll
  for (int j = 0; j < 6; ++j) { f[j] = __expf(mw[j] - M); S += sw[j] * f[j]; }
  const float invS = 1.0f / S;
  const float* redp = (const float*)redv4;
#pragma unroll
  for (int part = 0; part < 2; ++part) {
    const int col = part * 384 + tid;
    float o = 0.f;
#pragma unroll
    for (int j = 0; j < 6; ++j) o += redp[j * HDIM + col] * f[j];
    pooled[(size_t)n * HDIM + col] = o * invS;
  }
}

// ---------------- kernel 3: segment mean ----------------
__global__ __launch_bounds__(256) void segmean(const float* __restrict__ pooled,
                                               const void* __restrict__ smap,
                                               const unsigned* __restrict__ slots_s,
                                               float* __restrict__ out, int N) {
  __shared__ unsigned fsh;
  const int t = blockIdx.x, tid = threadIdx.x;
  const int col = blockIdx.y * 256 + tid;
  if (tid == 0) {
    unsigned f = 0;
    for (int i = 0; i < 64; ++i) f |= slots_s[i];
    fsh = f;
  }
  __syncthreads();
  const int smap_is_i32 = (fsh != 0);
  float a = 0.f;
  int cnt = 0;
  for (int i = 0; i < N; ++i) {
    const int s = smap_is_i32 ? ((const int*)smap)[i]
                              : (int)((const long long*)smap)[i];
    if (s == t) { a += pooled[(size_t)i * HDIM + col]; ++cnt; }
  }
  out[(size_t)t * HDIM + col] = a / (float)(cnt > 0 ? cnt : 1);
}

extern "C" void kernel_launch(void* const* d_in, const int* in_sizes, int n_in,
                              void* d_out, int out_size, void* d_ws, size_t ws_size,
                              hipStream_t stream) {
  const float*    hs     = (const float*)d_in[0];
  const unsigned* mask_w = (const unsigned*)d_in[1];
  const void*     smap   = d_in[2];
  const float*    Wq     = (const float*)d_in[3];
  const float*    bq     = (const float*)d_in[4];
  const float*    Wk     = (const float*)d_in[5];
  // d_in[6] = bk: dead (adds per-row constant to scores -> softmax-invariant)

  const int N = in_sizes[2];           // 512
  const int L = in_sizes[1] / N;       // 512
  const int H = in_sizes[4];           // 768 (== HDIM)
  const int T = out_size / H;          // 32

  float* Wc     = (float*)d_ws;                    // [H,H]
  float* c0     = Wc + (size_t)H * H;              // [H]
  float* pooled = c0 + H;                          // [N,H]
  unsigned* slots = (unsigned*)(pooled + (size_t)N * H);  // [128]
  (void)ws_size; (void)n_in;

  detect_slots<<<64, 256, 0, stream>>>(mask_w, (const unsigned*)smap, slots, N * L, N);
  prep_wc<<<dim3(H / 32, H / 64), 256, 0, stream>>>(Wq, Wk, bq, Wc, c0, H);
  fused<<<N, 384, 0, stream>>>(hs, mask_w, Wc, c0, slots, pooled, L);
  segmean<<<dim3(T, 3), 256, 0, stream>>>(pooled, smap, slots + 64, (float*)d_out, N);
}